// Round 3
// baseline (16388.083 us; speedup 1.0000x reference)
//
#include <hip/hip_runtime.h>
#include <hip/hip_bf16.h>
#include <math.h>

typedef __hip_bfloat16 bf16;

#define NW   16384   // B*S words
#define LC   20
#define EDIM 64
#define HC   256
#define HW   512
#define SEQ  128
#define NOUT 50
#define CW   2048    // words per char/MLP chunk
#define NCH  (NW / CW)

__device__ __forceinline__ float sigf(float x) { return 1.0f / (1.0f + expf(-x)); }
__device__ __forceinline__ float bu2f(unsigned short b) {
  union { float f; unsigned u; } z; z.u = ((unsigned)b) << 16; return z.f;
}
__device__ __forceinline__ unsigned short f2bu(float f) {
  bf16 h = __float2bfloat16(f);
  return *reinterpret_cast<unsigned short*>(&h);
}

// ---------------------------------------------------------------------------
// Two-segment GEMM: C[M,N] = [A1|A2] @ [Wa|Wb]^T + bias, f32 accumulate.
// A segments templated: 0 = f32, 1 = bf16(ushort). W segments always f32
// (device inputs are float32). C output f32. Tiles 64x64, BK=16, 256 thr.
// M, N multiples of 64; K1 and K2 multiples of 16; K2 may be 0.
// ---------------------------------------------------------------------------
struct GArgs {
  const void* A1; int lda1; int K1;
  const void* A2; int lda2; int K2;
  const float* Wa; int ldwa;   // cols [0, K1)
  const float* Wb; int ldwb;   // cols [K1, K1+K2)
  const float* bias;
  float* C; int ldc;
  int act;                     // 1 = relu
};

template <int A1T, int A2T>
__device__ __forceinline__ void gemm2_body(const GArgs g) {
  __shared__ float As[16][65];
  __shared__ float Ws[16][65];
  const int tid  = threadIdx.x;
  const int row0 = blockIdx.y * 64;
  const int col0 = blockIdx.x * 64;
  const int K    = g.K1 + g.K2;
  const int lm = tid >> 2;          // 0..63
  const int lk = (tid & 3) * 4;     // {0,4,8,12}
  const int ty = tid >> 4;          // 0..15
  const int tx = tid & 15;          // 0..15
  float acc[4][4] = {{0.f}};
  for (int k0 = 0; k0 < K; k0 += 16) {
    const int kg = k0 + lk;
    float a0, a1, a2, a3;
    float4 wv;
    if (kg < g.K1) {
      if (A1T) {
        ushort4 u = *reinterpret_cast<const ushort4*>(
            (const unsigned short*)g.A1 + (size_t)(row0 + lm) * g.lda1 + kg);
        a0 = bu2f(u.x); a1 = bu2f(u.y); a2 = bu2f(u.z); a3 = bu2f(u.w);
      } else {
        float4 f = *reinterpret_cast<const float4*>(
            (const float*)g.A1 + (size_t)(row0 + lm) * g.lda1 + kg);
        a0 = f.x; a1 = f.y; a2 = f.z; a3 = f.w;
      }
      wv = *reinterpret_cast<const float4*>(g.Wa + (size_t)(col0 + lm) * g.ldwa + kg);
    } else {
      const int k2 = kg - g.K1;
      if (A2T) {
        ushort4 u = *reinterpret_cast<const ushort4*>(
            (const unsigned short*)g.A2 + (size_t)(row0 + lm) * g.lda2 + k2);
        a0 = bu2f(u.x); a1 = bu2f(u.y); a2 = bu2f(u.z); a3 = bu2f(u.w);
      } else {
        float4 f = *reinterpret_cast<const float4*>(
            (const float*)g.A2 + (size_t)(row0 + lm) * g.lda2 + k2);
        a0 = f.x; a1 = f.y; a2 = f.z; a3 = f.w;
      }
      wv = *reinterpret_cast<const float4*>(g.Wb + (size_t)(col0 + lm) * g.ldwb + k2);
    }
    As[lk + 0][lm] = a0; As[lk + 1][lm] = a1; As[lk + 2][lm] = a2; As[lk + 3][lm] = a3;
    Ws[lk + 0][lm] = wv.x; Ws[lk + 1][lm] = wv.y; Ws[lk + 2][lm] = wv.z; Ws[lk + 3][lm] = wv.w;
    __syncthreads();
#pragma unroll
    for (int kk = 0; kk < 16; ++kk) {
      float a[4], w[4];
#pragma unroll
      for (int i = 0; i < 4; ++i) a[i] = As[kk][ty * 4 + i];
#pragma unroll
      for (int i = 0; i < 4; ++i) w[i] = Ws[kk][tx * 4 + i];
#pragma unroll
      for (int i = 0; i < 4; ++i)
#pragma unroll
        for (int j = 0; j < 4; ++j)
          acc[i][j] = fmaf(a[i], w[j], acc[i][j]);
    }
    __syncthreads();
  }
#pragma unroll
  for (int i = 0; i < 4; ++i) {
    const int r = row0 + ty * 4 + i;
    const int c = col0 + tx * 4;
    float v[4];
#pragma unroll
    for (int j = 0; j < 4; ++j) {
      float t = acc[i][j] + g.bias[c + j];
      if (g.act) t = fmaxf(t, 0.f);
      v[j] = t;
    }
    *reinterpret_cast<float4*>(g.C + (size_t)r * g.ldc + c) =
        make_float4(v[0], v[1], v[2], v[3]);
  }
}

__global__ __launch_bounds__(256) void gemm_ff(GArgs g) { gemm2_body<0, 0>(g); }
__global__ __launch_bounds__(256) void gemm_bb(GArgs g) { gemm2_body<1, 1>(g); }
__global__ __launch_bounds__(256) void gemm_dual_bf(GArgs g0, GArgs g1) {
  gemm2_body<1, 0>(blockIdx.z ? g1 : g0);
}

// ---------------------------------------------------------------------------
__global__ void bias_prep(const float* a, const float* b, float* dst, int n) {
  int i = blockIdx.x * blockDim.x + threadIdx.x;
  if (i < n) dst[i] = a[i] + (b ? b[i] : 0.f);
}

__global__ void lengths_k(const int* x, int* len) {
  int n = blockIdx.x * blockDim.x + threadIdx.x;
  if (n < NW) {
    int c = 0;
#pragma unroll
    for (int l = 0; l < LC; ++l) c += (x[(size_t)n * LC + l] != 0) ? 1 : 0;
    len[n] = c;
  }
}

// Ebuf[r,:] = emb[x[n0+r, t], :]  (f32), r in [0, CW)
__global__ void embed_k(const int* x, const float* emb, float* Ebuf, int t, int n0) {
  int idx = blockIdx.x * blockDim.x + threadIdx.x;   // CW*EDIM
  int r = idx >> 6, j = idx & 63;
  int ch = x[(size_t)(n0 + r) * LC + t];
  Ebuf[idx] = emb[(size_t)ch * EDIM + j];
}

__global__ void char_update(const float* __restrict__ gates, float* __restrict__ C,
                            float* __restrict__ H, unsigned short* __restrict__ last,
                            const int* __restrict__ len, int t, int n0) {
  int idx = blockIdx.x * blockDim.x + threadIdx.x;   // CW*HC
  int r = idx >> 8, u = idx & 255;
  const float* g = gates + (size_t)r * 1024;
  float i  = sigf(g[u]);
  float f  = sigf(g[256 + u]);
  float gg = tanhf(g[512 + u]);
  float o  = sigf(g[768 + u]);
  float cprev = t ? C[idx] : 0.f;
  float c = f * cprev + i * gg;
  C[idx] = c;
  float h = o * tanhf(c);
  H[idx] = h;
  int n = n0 + r;
  if (len[n] > t)      last[(size_t)n * HC + u] = f2bu(h);
  else if (t == 0)     last[(size_t)n * HC + u] = 0;   // bf16 +0
}

__global__ void word_update(const float* __restrict__ gates,
                            float* __restrict__ cfm, float* __restrict__ hfm,
                            float* __restrict__ cbm, float* __restrict__ hbm,
                            unsigned short* __restrict__ hsf, unsigned short* __restrict__ hsb,
                            int t) {
  int idx = blockIdx.x * blockDim.x + threadIdx.x;   // 2*SEQ*HW
  int dir = idx >> 16;
  int r = idx & 65535;
  int b = r >> 9, u = r & 511;
  const float* g = gates + (size_t)(dir * SEQ + b) * 2048;
  float*          c  = dir ? cbm : cfm;
  float*          h  = dir ? hbm : hfm;
  unsigned short* hs = dir ? hsb : hsf;
  float i  = sigf(g[u]);
  float f  = sigf(g[512 + u]);
  float gg = tanhf(g[1024 + u]);
  float o  = sigf(g[1536 + u]);
  float cprev = t ? c[r] : 0.f;
  float cn = f * cprev + i * gg;
  c[r] = cn;
  float hv = o * tanhf(cn);
  h[r] = hv;
  int pos = dir ? (SEQ - 1 - t) : t;
  hs[((size_t)b * SEQ + pos) * HW + u] = f2bu(hv);
}

// logits (N=50, K=256) + log_softmax; one wave per row, 4 rows per block
__global__ __launch_bounds__(256) void logits_lsm(const float* __restrict__ h2,
                                                  const float* __restrict__ W3,
                                                  const float* __restrict__ b3,
                                                  float* __restrict__ out, int n0) {
  int wave = threadIdx.x >> 6;
  int lane = threadIdx.x & 63;
  int row = blockIdx.x * 4 + wave;
  const float* hr = h2 + (size_t)row * 256;
  float acc = -INFINITY;
  if (lane < NOUT) {
    acc = b3[lane];
    const float* w = W3 + (size_t)lane * 256;
    for (int k = 0; k < 256; ++k) acc = fmaf(hr[k], w[k], acc);
  }
  float m = acc;
#pragma unroll
  for (int off = 32; off; off >>= 1) m = fmaxf(m, __shfl_xor(m, off));
  float e = (lane < NOUT) ? expf(acc - m) : 0.f;
  float s = e;
#pragma unroll
  for (int off = 32; off; off >>= 1) s += __shfl_xor(s, off);
  float lse = logf(s) + m;
  if (lane < NOUT) out[(size_t)(n0 + row) * NOUT + lane] = acc - lse;
}

__global__ void sentinel_k(float* out, int n) {
  int i = blockIdx.x * blockDim.x + threadIdx.x;
  if (i < n) out[i] = 1000.0f;
}

// ---------------------------------------------------------------------------
extern "C" void kernel_launch(void* const* d_in, const int* in_sizes, int n_in,
                              void* d_out, int out_size, void* d_ws, size_t ws_size,
                              hipStream_t stream) {
  const int*   x     = (const int*)d_in[0];
  const float* emb   = (const float*)d_in[1];
  const float* cW_ih = (const float*)d_in[2];
  const float* cW_hh = (const float*)d_in[3];
  const float* cb_ih = (const float*)d_in[4];
  const float* cb_hh = (const float*)d_in[5];
  const float* fW_ih = (const float*)d_in[6];
  const float* fW_hh = (const float*)d_in[7];
  const float* fb_ih = (const float*)d_in[8];
  const float* fb_hh = (const float*)d_in[9];
  const float* bW_ih = (const float*)d_in[10];
  const float* bW_hh = (const float*)d_in[11];
  const float* bb_ih = (const float*)d_in[12];
  const float* bb_hh = (const float*)d_in[13];
  const float* W1 = (const float*)d_in[14];
  const float* b1 = (const float*)d_in[15];
  const float* W2 = (const float*)d_in[16];
  const float* b2 = (const float*)d_in[17];
  const float* W3 = (const float*)d_in[18];
  const float* b3 = (const float*)d_in[19];
  float* out = (float*)d_out;
  (void)in_sizes; (void)n_in;

  char* ws = (char*)d_ws;
  size_t off = 0;
  auto alloc = [&](size_t bytes) -> char* {
    char* p = ws + off;
    off += (bytes + 255) & ~(size_t)255;
    return p;
  };
  int*   len_  = (int*)  alloc((size_t)NW * 4);
  float* bcS   = (float*)alloc(1024 * 4);
  float* bfS   = (float*)alloc(2048 * 4);
  float* bbS   = (float*)alloc(2048 * 4);
  float* b1c   = (float*)alloc(256 * 4);
  float* b2c   = (float*)alloc(256 * 4);
  float* b3c   = (float*)alloc(64 * 4);
  float* Ebuf  = (float*)alloc((size_t)CW * EDIM * 4);          // 0.5MB
  float* Hch   = (float*)alloc((size_t)CW * HC * 4);            // 2MB; later h1 chunk
  float* Cch   = (float*)alloc((size_t)CW * HC * 4);            // 2MB; later h2 chunk
  float* gates = (float*)alloc((size_t)CW * 1024 * 4);          // 8MB; word gates fit (2MB)
  unsigned short* last = (unsigned short*)alloc((size_t)NW * HC * 2);   // 8MB bf16
  float* hf_   = (float*)alloc((size_t)SEQ * HW * 4);
  float* hb_   = (float*)alloc((size_t)SEQ * HW * 4);
  float* cf_   = (float*)alloc((size_t)SEQ * HW * 4);
  float* cbst  = (float*)alloc((size_t)SEQ * HW * 4);
  unsigned short* hs_f = (unsigned short*)alloc((size_t)NW * HW * 2);   // 16MB bf16
  unsigned short* hs_b = (unsigned short*)alloc((size_t)NW * HW * 2);   // 16MB bf16
  float* h1ch = Hch;
  float* h2ch = Cch;

  if (off > ws_size) {   // workspace too small -> unambiguous sentinel output
    sentinel_k<<<(out_size + 255) / 256, 256, 0, stream>>>(out, out_size);
    return;
  }

  auto cdiv = [](long a, long b) { return (int)((a + b - 1) / b); };

  // ---- prep ----
  bias_prep<<<cdiv(1024, 256), 256, 0, stream>>>(cb_ih, cb_hh, bcS, 1024);
  bias_prep<<<cdiv(2048, 256), 256, 0, stream>>>(fb_ih, fb_hh, bfS, 2048);
  bias_prep<<<cdiv(2048, 256), 256, 0, stream>>>(bb_ih, bb_hh, bbS, 2048);
  bias_prep<<<1, 256, 0, stream>>>(b1, nullptr, b1c, 256);
  bias_prep<<<1, 256, 0, stream>>>(b2, nullptr, b2c, 256);
  bias_prep<<<1, 256, 0, stream>>>(b3, nullptr, b3c, NOUT);
  lengths_k<<<cdiv(NW, 256), 256, 0, stream>>>(x, len_);

  // ---- char LSTM: 8 chunks x 20 steps ----
  for (int ch = 0; ch < NCH; ++ch) {
    const int n0 = ch * CW;
    for (int t = 0; t < LC; ++t) {
      embed_k<<<CW * EDIM / 256, 256, 0, stream>>>(x, emb, Ebuf, t, n0);
      GArgs g;
      g.A1 = Ebuf; g.lda1 = EDIM; g.K1 = EDIM;
      g.A2 = Hch;  g.lda2 = HC;   g.K2 = (t == 0) ? 0 : HC;
      g.Wa = cW_ih; g.ldwa = EDIM;
      g.Wb = cW_hh; g.ldwb = HC;
      g.bias = bcS; g.C = gates; g.ldc = 1024; g.act = 0;
      gemm_ff<<<dim3(1024 / 64, CW / 64), 256, 0, stream>>>(g);
      char_update<<<CW * HC / 256, 256, 0, stream>>>(gates, Cch, Hch, last, len_, t, n0);
    }
  }

  // ---- word BiLSTM: 128 steps, fwd+bwd fused per launch ----
  for (int t = 0; t < SEQ; ++t) {
    GArgs gf, gb;
    gf.A1 = last + (size_t)t * HC; gf.lda1 = SEQ * HC; gf.K1 = HC;
    gf.A2 = hf_; gf.lda2 = HW; gf.K2 = (t == 0) ? 0 : HW;
    gf.Wa = fW_ih; gf.ldwa = HC;
    gf.Wb = fW_hh; gf.ldwb = HW;
    gf.bias = bfS; gf.C = gates; gf.ldc = 2048; gf.act = 0;
    gb = gf;
    gb.A1 = last + (size_t)(SEQ - 1 - t) * HC;
    gb.A2 = hb_;
    gb.Wa = bW_ih; gb.Wb = bW_hh; gb.bias = bbS;
    gb.C = gates + (size_t)SEQ * 2048;
    gemm_dual_bf<<<dim3(2048 / 64, SEQ / 64, 2), 256, 0, stream>>>(gf, gb);
    word_update<<<2 * SEQ * HW / 256, 256, 0, stream>>>(gates, cf_, hf_, cbst, hb_,
                                                        hs_f, hs_b, t);
  }

  // ---- MLP + log_softmax: 8 chunks ----
  for (int ch = 0; ch < NCH; ++ch) {
    const int n0 = ch * CW;
    GArgs m1;
    m1.A1 = hs_f + (size_t)n0 * HW; m1.lda1 = HW; m1.K1 = HW;
    m1.A2 = hs_b + (size_t)n0 * HW; m1.lda2 = HW; m1.K2 = HW;
    m1.Wa = W1; m1.ldwa = 2 * HW;
    m1.Wb = W1 + HW; m1.ldwb = 2 * HW;
    m1.bias = b1c; m1.C = h1ch; m1.ldc = 256; m1.act = 1;
    gemm_bb<<<dim3(256 / 64, CW / 64), 256, 0, stream>>>(m1);
    GArgs m2;
    m2.A1 = h1ch; m2.lda1 = 256; m2.K1 = 256;
    m2.A2 = nullptr; m2.lda2 = 0; m2.K2 = 0;
    m2.Wa = W2; m2.ldwa = 256;
    m2.Wb = nullptr; m2.ldwb = 0;
    m2.bias = b2c; m2.C = h2ch; m2.ldc = 256; m2.act = 1;
    gemm_ff<<<dim3(256 / 64, CW / 64), 256, 0, stream>>>(m2);
    logits_lsm<<<CW / 4, 256, 0, stream>>>(h2ch, W3, b3c, out, n0);
  }
}

// Round 4
// 4772.787 us; speedup vs baseline: 3.4337x; 3.4337x over previous
//
#include <hip/hip_runtime.h>
#include <hip/hip_bf16.h>
#include <math.h>

typedef __hip_bfloat16 bf16;
typedef __attribute__((ext_vector_type(8))) short bf16x8;   // 8 bf16 = 4 VGPR
typedef __attribute__((ext_vector_type(4))) float f32x4;

#define NW   16384
#define LC   20
#define EDIM 64
#define HC   256
#define HW   512
#define SEQ  128
#define NOUT 50

__device__ __forceinline__ float sigf(float x) { return 1.0f / (1.0f + expf(-x)); }
__device__ __forceinline__ float bu2f(unsigned short b) {
  union { float f; unsigned u; } z; z.u = ((unsigned)b) << 16; return z.f;
}
__device__ __forceinline__ unsigned short f2bu(float f) {
  bf16 h = __float2bfloat16(f);
  return *reinterpret_cast<unsigned short*>(&h);
}
__device__ __forceinline__ bf16x8 ld8(const unsigned short* p) {
  return *reinterpret_cast<const bf16x8*>(p);
}
#define MFMA(a, b, c) __builtin_amdgcn_mfma_f32_16x16x32_bf16(a, b, c, 0, 0, 0)

// ---------------------------------------------------------------------------
// Char LSTM step, fully fused: gates = [E_t | H] @ Wc'^T (MFMA) -> LDS ->
// LSTM update -> H/C/last. Wc' is gate-interleaved (row 4u+g), bf16.
// Block: BM=128 rows x BN=64 cols, 4 waves (each 32 rows x 64 cols, 2x4 frags).
// Grid: (1024/64=16, NW/128=128). H double-buffered across steps (cross-block
// read hazard); C/last/Hout are uniquely owned per (row,unit) -> no race.
// ---------------------------------------------------------------------------
__global__ __launch_bounds__(256) void char_step(
    const int* __restrict__ x, const unsigned short* __restrict__ embb,
    const unsigned short* __restrict__ Wc, const float* __restrict__ bc,
    const unsigned short* __restrict__ Hin, unsigned short* __restrict__ Hout,
    float* __restrict__ Cst, unsigned short* __restrict__ last,
    const int* __restrict__ len, int t) {
  __shared__ float gt[128][65];
  const int tid = threadIdx.x;
  const int w = tid >> 6, l = tid & 63;
  const int l16 = l & 15, lk8 = (l >> 4) * 8;
  const int row0 = blockIdx.y * 128;
  const int col0 = blockIdx.x * 64;
  const int r0 = row0 + w * 32 + l16;        // A row, frag m=0
  const int r1 = r0 + 16;                    // frag m=1
  const int xi0 = x[r0 * LC + t];
  const int xi1 = x[r1 * LC + t];
  f32x4 acc[2][4] = {};
  const int nk = (t == 0) ? 2 : 10;          // K=64 (E only) or 320
  for (int kk = 0; kk < nk; ++kk) {
    const int k = kk * 32 + lk8;
    bf16x8 a0, a1;
    if (k < EDIM) {
      a0 = ld8(embb + (size_t)xi0 * EDIM + k);
      a1 = ld8(embb + (size_t)xi1 * EDIM + k);
    } else {
      a0 = ld8(Hin + (size_t)r0 * HC + (k - EDIM));
      a1 = ld8(Hin + (size_t)r1 * HC + (k - EDIM));
    }
    const unsigned short* wp = Wc + (size_t)(col0 + l16) * 320 + k;
    bf16x8 bb[4];
#pragma unroll
    for (int n = 0; n < 4; ++n) bb[n] = ld8(wp + n * 16 * 320);
#pragma unroll
    for (int n = 0; n < 4; ++n) {
      acc[0][n] = MFMA(a0, bb[n], acc[0][n]);
      acc[1][n] = MFMA(a1, bb[n], acc[1][n]);
    }
  }
  const int cr = (l >> 4) * 4;
#pragma unroll
  for (int m = 0; m < 2; ++m)
#pragma unroll
    for (int n = 0; n < 4; ++n)
#pragma unroll
      for (int e = 0; e < 4; ++e)
        gt[w * 32 + m * 16 + cr + e][n * 16 + l16] = acc[m][n][e];
  __syncthreads();
  const int u0 = col0 >> 2;
  for (int it = tid; it < 128 * 16; it += 256) {
    const int row = it >> 4, ul = it & 15;
    const int cb = col0 + 4 * ul;
    float gi = gt[row][4 * ul + 0] + bc[cb + 0];
    float gf = gt[row][4 * ul + 1] + bc[cb + 1];
    float gg = gt[row][4 * ul + 2] + bc[cb + 2];
    float go = gt[row][4 * ul + 3] + bc[cb + 3];
    const size_t nrow = row0 + row;
    const int unit = u0 + ul;
    const size_t idx = nrow * HC + unit;
    float cprev = t ? Cst[idx] : 0.f;
    float c = sigf(gf) * cprev + sigf(gi) * tanhf(gg);
    Cst[idx] = c;
    float h = sigf(go) * tanhf(c);
    Hout[idx] = f2bu(h);
    if (len[nrow] > t)   last[idx] = f2bu(h);
    else if (t == 0)     last[idx] = 0;      // bf16 +0
  }
}

// ---------------------------------------------------------------------------
// Word BiLSTM step, fused. A = [word_seq[:,pos] | h_prev], K=768 (256+512).
// Grid: (2048/64=32, 1, 2 dirs). BM=128 covers all batches. h double-buffered.
// ---------------------------------------------------------------------------
__global__ __launch_bounds__(256) void word_step(
    const unsigned short* __restrict__ last,
    const unsigned short* __restrict__ Wf, const unsigned short* __restrict__ Wb,
    const float* __restrict__ bfi, const float* __restrict__ bbi,
    const unsigned short* __restrict__ hin, unsigned short* __restrict__ hout,
    float* __restrict__ cst, unsigned short* __restrict__ hs, int t) {
  __shared__ float gt[128][65];
  const int dir = blockIdx.z;
  const int pos = dir ? (SEQ - 1 - t) : t;
  const unsigned short* W = dir ? Wb : Wf;
  const float* bias = dir ? bbi : bfi;
  const int tid = threadIdx.x;
  const int w = tid >> 6, l = tid & 63;
  const int l16 = l & 15, lk8 = (l >> 4) * 8;
  const int col0 = blockIdx.x * 64;
  const int bt0 = w * 32 + l16;              // batch, frag m=0
  const unsigned short* hbase = hin + (size_t)dir * SEQ * HW;
  f32x4 acc[2][4] = {};
  const int nk = (t == 0) ? 8 : 24;          // K=256 or 768
  for (int kk = 0; kk < nk; ++kk) {
    const int k = kk * 32 + lk8;
    bf16x8 a0, a1;
    if (k < HC) {
      a0 = ld8(last + ((size_t)bt0 * SEQ + pos) * HC + k);
      a1 = ld8(last + ((size_t)(bt0 + 16) * SEQ + pos) * HC + k);
    } else {
      a0 = ld8(hbase + (size_t)bt0 * HW + (k - HC));
      a1 = ld8(hbase + (size_t)(bt0 + 16) * HW + (k - HC));
    }
    const unsigned short* wp = W + (size_t)(col0 + l16) * 768 + k;
    bf16x8 bb[4];
#pragma unroll
    for (int n = 0; n < 4; ++n) bb[n] = ld8(wp + n * 16 * 768);
#pragma unroll
    for (int n = 0; n < 4; ++n) {
      acc[0][n] = MFMA(a0, bb[n], acc[0][n]);
      acc[1][n] = MFMA(a1, bb[n], acc[1][n]);
    }
  }
  const int cr = (l >> 4) * 4;
#pragma unroll
  for (int m = 0; m < 2; ++m)
#pragma unroll
    for (int n = 0; n < 4; ++n)
#pragma unroll
      for (int e = 0; e < 4; ++e)
        gt[w * 32 + m * 16 + cr + e][n * 16 + l16] = acc[m][n][e];
  __syncthreads();
  const int u0 = col0 >> 2;
  for (int it = tid; it < 128 * 16; it += 256) {
    const int b = it >> 4, ul = it & 15;
    const int cb = col0 + 4 * ul;
    float gi = gt[b][4 * ul + 0] + bias[cb + 0];
    float gf = gt[b][4 * ul + 1] + bias[cb + 1];
    float gg = gt[b][4 * ul + 2] + bias[cb + 2];
    float go = gt[b][4 * ul + 3] + bias[cb + 3];
    const int unit = u0 + ul;
    const size_t sidx = (size_t)(dir * SEQ + b) * HW + unit;
    float cprev = t ? cst[sidx] : 0.f;
    float c = sigf(gf) * cprev + sigf(gi) * tanhf(gg);
    cst[sidx] = c;
    float h = sigf(go) * tanhf(c);
    hout[sidx] = f2bu(h);
    hs[((size_t)b * SEQ + pos) * 1024 + dir * HW + unit] = f2bu(h);
  }
}

// ---------------------------------------------------------------------------
// MLP GEMM: out[r][c] = relu(A[r][:] . W[c][:] + bias[c]), bf16 in/out.
// Block: 128 rows x 64 cols, 4 waves. Direct per-lane bf16 stores.
// ---------------------------------------------------------------------------
__global__ __launch_bounds__(256) void mlp_gemm(
    const unsigned short* __restrict__ A, int lda,
    const unsigned short* __restrict__ W, int ldw,
    const float* __restrict__ bias, unsigned short* __restrict__ out,
    int ldo, int nk, int relu) {
  const int tid = threadIdx.x;
  const int w = tid >> 6, l = tid & 63;
  const int l16 = l & 15, lk8 = (l >> 4) * 8;
  const int row0 = blockIdx.y * 128 + w * 32;
  const int col0 = blockIdx.x * 64;
  f32x4 acc[2][4] = {};
  for (int kk = 0; kk < nk; ++kk) {
    const int k = kk * 32 + lk8;
    bf16x8 a0 = ld8(A + (size_t)(row0 + l16) * lda + k);
    bf16x8 a1 = ld8(A + (size_t)(row0 + 16 + l16) * lda + k);
    const unsigned short* wp = W + (size_t)(col0 + l16) * ldw + k;
    bf16x8 bb[4];
#pragma unroll
    for (int n = 0; n < 4; ++n) bb[n] = ld8(wp + n * 16 * ldw);
#pragma unroll
    for (int n = 0; n < 4; ++n) {
      acc[0][n] = MFMA(a0, bb[n], acc[0][n]);
      acc[1][n] = MFMA(a1, bb[n], acc[1][n]);
    }
  }
  const int cr = (l >> 4) * 4;
#pragma unroll
  for (int m = 0; m < 2; ++m)
#pragma unroll
    for (int n = 0; n < 4; ++n)
#pragma unroll
      for (int e = 0; e < 4; ++e) {
        const int r = row0 + m * 16 + cr + e;
        const int c = col0 + n * 16 + l16;
        float v = acc[m][n][e] + bias[c];
        if (relu) v = fmaxf(v, 0.f);
        out[(size_t)r * ldo + c] = f2bu(v);
      }
}

// ---------------------------------------------------------------------------
// Prep: gate-interleaved bf16 weights (row 4u+g <- row g*HU+u of [ih|hh]),
// interleaved bias sums, plain f32->bf16 conversion, word lengths.
// ---------------------------------------------------------------------------
__global__ void prep_w(const float* __restrict__ ih, const float* __restrict__ hh,
                       unsigned short* __restrict__ dst, int HU, int KI, int KH) {
  const int K = KI + KH;
  const long tot = (long)HU * 4 * K;
  for (long idx = (long)blockIdx.x * blockDim.x + threadIdx.x; idx < tot;
       idx += (long)gridDim.x * blockDim.x) {
    const int row = (int)(idx / K), k = (int)(idx % K);
    const int u = row >> 2, g = row & 3;
    const float v = (k < KI) ? ih[(size_t)(g * HU + u) * KI + k]
                             : hh[(size_t)(g * HU + u) * KH + (k - KI)];
    dst[idx] = f2bu(v);
  }
}

__global__ void prep_bias(const float* bih, const float* bhh, float* dst, int HU) {
  const int idx = blockIdx.x * blockDim.x + threadIdx.x;
  if (idx < 4 * HU) {
    const int u = idx >> 2, g = idx & 3;
    dst[idx] = bih[g * HU + u] + bhh[g * HU + u];
  }
}

__global__ void conv_bf(const float* __restrict__ src, unsigned short* __restrict__ dst,
                        long n) {
  for (long i = (long)blockIdx.x * blockDim.x + threadIdx.x; i < n;
       i += (long)gridDim.x * blockDim.x)
    dst[i] = f2bu(src[i]);
}

__global__ void lengths_k(const int* x, int* len) {
  const int n = blockIdx.x * blockDim.x + threadIdx.x;
  if (n < NW) {
    int c = 0;
#pragma unroll
    for (int l = 0; l < LC; ++l) c += (x[(size_t)n * LC + l] != 0) ? 1 : 0;
    len[n] = c;
  }
}

// logits (N=50, K=256) + log_softmax; one wave per row
__global__ __launch_bounds__(256) void logits_lsm(const unsigned short* __restrict__ h2,
                                                  const float* __restrict__ W3,
                                                  const float* __restrict__ b3,
                                                  float* __restrict__ out) {
  const int wave = threadIdx.x >> 6;
  const int lane = threadIdx.x & 63;
  const int row = blockIdx.x * 4 + wave;
  const unsigned short* hr = h2 + (size_t)row * 256;
  float acc = -INFINITY;
  if (lane < NOUT) {
    acc = b3[lane];
    const float* wv = W3 + (size_t)lane * 256;
    for (int k = 0; k < 256; ++k) acc = fmaf(bu2f(hr[k]), wv[k], acc);
  }
  float m = acc;
#pragma unroll
  for (int off = 32; off; off >>= 1) m = fmaxf(m, __shfl_xor(m, off));
  float e = (lane < NOUT) ? expf(acc - m) : 0.f;
  float s = e;
#pragma unroll
  for (int off = 32; off; off >>= 1) s += __shfl_xor(s, off);
  const float lse = logf(s) + m;
  if (lane < NOUT) out[(size_t)row * NOUT + lane] = acc - lse;
}

__global__ void sentinel_k(float* out, int n) {
  const int i = blockIdx.x * blockDim.x + threadIdx.x;
  if (i < n) out[i] = 1000.0f;
}

// ---------------------------------------------------------------------------
extern "C" void kernel_launch(void* const* d_in, const int* in_sizes, int n_in,
                              void* d_out, int out_size, void* d_ws, size_t ws_size,
                              hipStream_t stream) {
  const int*   x     = (const int*)d_in[0];
  const float* emb   = (const float*)d_in[1];
  const float* cW_ih = (const float*)d_in[2];
  const float* cW_hh = (const float*)d_in[3];
  const float* cb_ih = (const float*)d_in[4];
  const float* cb_hh = (const float*)d_in[5];
  const float* fW_ih = (const float*)d_in[6];
  const float* fW_hh = (const float*)d_in[7];
  const float* fb_ih = (const float*)d_in[8];
  const float* fb_hh = (const float*)d_in[9];
  const float* bW_ih = (const float*)d_in[10];
  const float* bW_hh = (const float*)d_in[11];
  const float* bb_ih = (const float*)d_in[12];
  const float* bb_hh = (const float*)d_in[13];
  const float* W1 = (const float*)d_in[14];
  const float* b1 = (const float*)d_in[15];
  const float* W2 = (const float*)d_in[16];
  const float* b2 = (const float*)d_in[17];
  const float* W3 = (const float*)d_in[18];
  const float* b3 = (const float*)d_in[19];
  float* out = (float*)d_out;
  (void)in_sizes; (void)n_in;

  char* ws = (char*)d_ws;
  size_t off = 0;
  auto alloc = [&](size_t bytes) -> char* {
    char* p = ws + off;
    off += (bytes + 255) & ~(size_t)255;
    return p;
  };
  int*            len_ = (int*)alloc((size_t)NW * 4);
  unsigned short* embb = (unsigned short*)alloc((size_t)100 * EDIM * 2);
  unsigned short* Wc_i = (unsigned short*)alloc((size_t)1024 * 320 * 2);
  unsigned short* Wf_i = (unsigned short*)alloc((size_t)2048 * 768 * 2);
  unsigned short* Wb_i = (unsigned short*)alloc((size_t)2048 * 768 * 2);
  unsigned short* W1b  = (unsigned short*)alloc((size_t)256 * 1024 * 2);
  unsigned short* W2b  = (unsigned short*)alloc((size_t)256 * 256 * 2);
  float*          bc_i = (float*)alloc(1024 * 4);
  float*          bf_i = (float*)alloc(2048 * 4);
  float*          bb_i = (float*)alloc(2048 * 4);
  unsigned short* Hb0  = (unsigned short*)alloc((size_t)NW * HC * 2);
  unsigned short* Hb1  = (unsigned short*)alloc((size_t)NW * HC * 2);
  float*          Cst  = (float*)alloc((size_t)NW * HC * 4);
  unsigned short* last = (unsigned short*)alloc((size_t)NW * HC * 2);
  unsigned short* hw0  = (unsigned short*)alloc((size_t)2 * SEQ * HW * 2);
  unsigned short* hw1  = (unsigned short*)alloc((size_t)2 * SEQ * HW * 2);
  float*          cw   = (float*)alloc((size_t)2 * SEQ * HW * 4);
  unsigned short* hs   = (unsigned short*)alloc((size_t)NW * 1024 * 2);
  // MLP intermediates reuse Cst (dead after char stage): 2 x 8MB inside 16MB
  unsigned short* h1 = (unsigned short*)Cst;
  unsigned short* h2 = (unsigned short*)Cst + (size_t)NW * HC;

  if (off > ws_size) {
    sentinel_k<<<(out_size + 255) / 256, 256, 0, stream>>>(out, out_size);
    return;
  }

  auto cdiv = [](long a, long b) { return (int)((a + b - 1) / b); };

  // ---- prep ----
  prep_w<<<1280, 256, 0, stream>>>(cW_ih, cW_hh, Wc_i, HC, EDIM, HC);
  prep_w<<<3072, 256, 0, stream>>>(fW_ih, fW_hh, Wf_i, HW, HC, HW);
  prep_w<<<3072, 256, 0, stream>>>(bW_ih, bW_hh, Wb_i, HW, HC, HW);
  prep_bias<<<cdiv(1024, 256), 256, 0, stream>>>(cb_ih, cb_hh, bc_i, HC);
  prep_bias<<<cdiv(2048, 256), 256, 0, stream>>>(fb_ih, fb_hh, bf_i, HW);
  prep_bias<<<cdiv(2048, 256), 256, 0, stream>>>(bb_ih, bb_hh, bb_i, HW);
  conv_bf<<<25, 256, 0, stream>>>(emb, embb, 100L * EDIM);
  conv_bf<<<1024, 256, 0, stream>>>(W1, W1b, 256L * 1024);
  conv_bf<<<256, 256, 0, stream>>>(W2, W2b, 256L * 256);
  lengths_k<<<cdiv(NW, 256), 256, 0, stream>>>(x, len_);

  // ---- char LSTM: 20 fused steps over all 16384 words ----
  for (int t = 0; t < LC; ++t) {
    const unsigned short* Hin  = (t & 1) ? Hb1 : Hb0;
    unsigned short*       Hout = (t & 1) ? Hb0 : Hb1;
    char_step<<<dim3(16, 128), 256, 0, stream>>>(x, embb, Wc_i, bc_i, Hin, Hout,
                                                 Cst, last, len_, t);
  }

  // ---- word BiLSTM: 128 fused steps ----
  for (int t = 0; t < SEQ; ++t) {
    const unsigned short* hin  = (t & 1) ? hw1 : hw0;
    unsigned short*       hout = (t & 1) ? hw0 : hw1;
    word_step<<<dim3(32, 1, 2), 256, 0, stream>>>(last, Wf_i, Wb_i, bf_i, bb_i,
                                                  hin, hout, cw, hs, t);
  }

  // ---- MLP + log_softmax ----
  mlp_gemm<<<dim3(4, 128), 256, 0, stream>>>(hs, 1024, W1b, 1024, b1, h1, 256, 32, 1);
  mlp_gemm<<<dim3(4, 128), 256, 0, stream>>>(h1, 256, W2b, 256, b2, h2, 256, 8, 1);
  logits_lsm<<<NW / 4, 256, 0, stream>>>(h2, W3, b3, out);
}